// Round 6
// baseline (1102.811 us; speedup 1.0000x reference)
//
#include <hip/hip_runtime.h>
#include <hip/hip_bf16.h>

// ---------------- problem constants ----------------
#define NTOK   8192
#define TOPK   2
#define NROWS  (NTOK*TOPK)      // 16384
#define NEXP   8
#define KDIM   1024             // inner (INTER)
#define NDIM   2048             // output (HIDDEN)
#define TM     256              // block tile rows (4 waves x 64)
#define TN     64               // block tile cols
#define MAXYT  72               // sum ceil(cnt_e/256) <= 64+8
#define NXT    (NDIM/TN)        // 32
#define GRID_G (MAXYT*NXT)      // 2304, divisible by 8

typedef __bf16 bf16_t;
typedef __bf16 bf16x8 __attribute__((ext_vector_type(8)));
typedef __bf16 bf16x4 __attribute__((ext_vector_type(4)));
typedef float  f32x4  __attribute__((ext_vector_type(4)));

static_assert(sizeof(bf16x8) == 16, "bf16x8 must be 16B");

// ---------------- ws layout (bytes) ----------------
#define OFF_TW    ((size_t)0)                    // 16384 f32 = 64KB
#define OFF_CNT   ((size_t)(1<<16))              // 8 i32
#define OFF_RL    ((size_t)(1<<18))              // 8*16384 i32 = 512KB
#define OFF_WB    ((size_t)(1<<20))              // 8*2048*1024 bf16 = 32MB
#define OFF_SCR   ((size_t)(34u<<20))            // 16384*2048 bf16 = 64MB
#define NEED_BF16 (OFF_SCR + (size_t)NROWS*NDIM*2)   // ~98MB

// ---------------- 1. routing: softmax + top2 + bucket (fused) ----------------
__global__ void routing_kernel(const float* __restrict__ logits,
                               float* __restrict__ tw,
                               int* __restrict__ cnt, int* __restrict__ rowlist) {
  int t = blockIdx.x * blockDim.x + threadIdx.x;
  if (t >= NTOK) return;
  float4 a = *(const float4*)(logits + (size_t)t*NEXP);
  float4 b = *(const float4*)(logits + (size_t)t*NEXP + 4);
  float l[8] = {a.x, a.y, a.z, a.w, b.x, b.y, b.z, b.w};
  float m = l[0];
#pragma unroll
  for (int i = 1; i < 8; i++) m = fmaxf(m, l[i]);
  float p[8], s = 0.f;
#pragma unroll
  for (int i = 0; i < 8; i++) { p[i] = __expf(l[i] - m); s += p[i]; }
  int e0 = 0; float b0 = p[0];
#pragma unroll
  for (int i = 1; i < 8; i++) if (p[i] > b0) { b0 = p[i]; e0 = i; }
  int e1 = (e0 == 0) ? 1 : 0; float b1 = p[e1];
#pragma unroll
  for (int i = 0; i < 8; i++) if (i != e0 && p[i] > b1) { b1 = p[i]; e1 = i; }
  float inv = 1.f / s;
  tw[2*t]   = b0 * inv;
  tw[2*t+1] = b1 * inv;
  int pos0 = atomicAdd(&cnt[e0], 1);
  rowlist[(size_t)e0*NROWS + pos0] = 2*t;
  int pos1 = atomicAdd(&cnt[e1], 1);
  rowlist[(size_t)e1*NROWS + pos1] = 2*t + 1;
}

// ---------------- 2. convert+transpose w -> bf16 [E][N][K] ----------------
__global__ void cvt_w_kernel(const float* __restrict__ w, bf16_t* __restrict__ wb) {
  __shared__ float tf[64*65];
  int e  = blockIdx.z;
  int n0 = blockIdx.x * 64;
  int k0 = blockIdx.y * 64;
  int t  = threadIdx.x;
  const float* src = w + (size_t)e*KDIM*NDIM + (size_t)k0*NDIM + n0;
#pragma unroll
  for (int i = 0; i < 4; i++) {
    int idx = t + i*256;
    int kr  = idx >> 4;
    int nc4 = (idx & 15) * 4;
    float4 v = *(const float4*)(src + (size_t)kr*NDIM + nc4);
    tf[kr*65 + nc4+0] = v.x; tf[kr*65 + nc4+1] = v.y;
    tf[kr*65 + nc4+2] = v.z; tf[kr*65 + nc4+3] = v.w;
  }
  __syncthreads();
  bf16_t* dst = wb + (size_t)e*NDIM*KDIM + (size_t)n0*KDIM + k0;
#pragma unroll
  for (int i = 0; i < 2; i++) {
    int idx = t + i*256;
    int nr  = idx >> 3;
    int kc  = (idx & 7) * 8;
    bf16x8 o;
#pragma unroll
    for (int j = 0; j < 8; j++) o[j] = (bf16_t)tf[(kc+j)*65 + nr];
    *(bf16x8*)(dst + (size_t)nr*KDIM + kc) = o;
  }
}

// ---------------- 3. grouped GEMM: 256x64 tile, BK=32, A-in-registers --------
// 4 waves stacked in M; each wave owns 64 rows -> A loaded per-lane from fp32 x
// (global->reg->cvt->MFMA, no LDS). Only B staged in LDS (4KB, single buffer,
// XOR-slot swizzle p = l ^ ((row>>1)&3), r2-proven conflict-free).
// Prefetch for step k+1 issues before step k's MFMAs; __syncthreads' vmcnt(0)
// lands exactly where the loads are consumed -> free pipelining.
// MODE 1: bf16 scratch   MODE 2: atomic into out
template <int MODE>
__global__ void gemm_kernel(const float*  __restrict__ x,      // [NROWS][KDIM] fp32
                            const bf16_t* __restrict__ wb,     // [NEXP][NDIM][KDIM]
                            const int*    __restrict__ rowlist,
                            const int*    __restrict__ cnt,
                            const float*  __restrict__ tw,
                            bf16_t*       __restrict__ scrb,
                            float*        __restrict__ outp) {
  __shared__ bf16_t Bs[TN * 32];   // 4KB

  // XCD-bijective swizzle: 2304 = 8 * 288
  int bid = blockIdx.x;
  int lin = (bid & 7) * (GRID_G/8) + (bid >> 3);
  int xt  = lin & (NXT-1);         // n-tile fastest -> A-chunk reuse in L2
  int yt  = lin >> 5;              // row-tile 0..71

  // inline worklist from cnt (row tiles of 256)
  int e = -1, rb = 0, nrows = 0, a0 = 0;
#pragma unroll
  for (int ee = 0; ee < NEXP; ee++) {
    int c  = cnt[ee];
    int nt = (c + 255) >> 8;
    if (yt >= a0 && yt < a0 + nt) {
      e = ee; rb = (yt - a0) << 8;
      nrows = c - rb; if (nrows > 256) nrows = 256;
    }
    a0 += nt;
  }
  if (e < 0) return;
  const int n0 = xt * TN;

  const int t    = threadIdx.x;
  const int lane = t & 63;
  const int wv   = t >> 6;         // 0..3 (M position)
  const int lr   = lane & 15;
  const int l4   = lane >> 4;

  const int* rl = rowlist + (size_t)e*NROWS + rb;

  // ---- A: per-lane row pointers (4 rows x 32B per step, col l4*8) ----
  const float* pr0; const float* pr1; const float* pr2; const float* pr3;
  {
    int r0 = wv*64 +  0 + lr, r1 = wv*64 + 16 + lr,
        r2 = wv*64 + 32 + lr, r3 = wv*64 + 48 + lr;
    pr0 = x + (size_t)rl[r0 < nrows ? r0 : nrows-1]*KDIM + l4*8;
    pr1 = x + (size_t)rl[r1 < nrows ? r1 : nrows-1]*KDIM + l4*8;
    pr2 = x + (size_t)rl[r2 < nrows ? r2 : nrows-1]*KDIM + l4*8;
    pr3 = x + (size_t)rl[r3 < nrows ? r3 : nrows-1]*KDIM + l4*8;
  }

  // ---- B staging: thread t -> row t>>2, phys slot t&3, logical = p^((row>>1)&3)
  const int brow  = t >> 2;
  const int kslot = ((t & 3) ^ ((t >> 3) & 3)) * 8;
  const bf16_t* gB = wb + ((size_t)e*NDIM + n0 + brow)*KDIM + kslot;
  const int bwo = brow*32 + (t & 3)*8;     // LDS write offset (elements)

  // ---- B fragment read offsets (swizzled) ----
  int bro[4];
#pragma unroll
  for (int ni = 0; ni < 4; ni++) {
    int row = ni*16 + lr;
    bro[ni] = row*32 + ((l4 ^ ((row >> 1) & 3)) << 3);
  }

  f32x4 acc[4][4] = {};

  // ---- prefetch k=0 ----
  f32x4 la0, la1, la2, la3, la4, la5, la6, la7; bf16x8 lb;
  la0 = *(const f32x4*)(pr0); la1 = *(const f32x4*)(pr0+4); pr0 += 32;
  la2 = *(const f32x4*)(pr1); la3 = *(const f32x4*)(pr1+4); pr1 += 32;
  la4 = *(const f32x4*)(pr2); la5 = *(const f32x4*)(pr2+4); pr2 += 32;
  la6 = *(const f32x4*)(pr3); la7 = *(const f32x4*)(pr3+4); pr3 += 32;
  lb  = *(const bf16x8*)(gB); gB += 32;

#pragma unroll 1
  for (int k = 0; k < 32; ++k) {
    __syncthreads();                 // prev Bs reads done; drains our prefetch
    *(bf16x8*)&Bs[bwo] = lb;         // stage B(k)
    bf16x8 abf[4];                   // cvt A(k) in-register
    abf[0] = bf16x8{ (bf16_t)la0[0],(bf16_t)la0[1],(bf16_t)la0[2],(bf16_t)la0[3],
                     (bf16_t)la1[0],(bf16_t)la1[1],(bf16_t)la1[2],(bf16_t)la1[3] };
    abf[1] = bf16x8{ (bf16_t)la2[0],(bf16_t)la2[1],(bf16_t)la2[2],(bf16_t)la2[3],
                     (bf16_t)la3[0],(bf16_t)la3[1],(bf16_t)la3[2],(bf16_t)la3[3] };
    abf[2] = bf16x8{ (bf16_t)la4[0],(bf16_t)la4[1],(bf16_t)la4[2],(bf16_t)la4[3],
                     (bf16_t)la5[0],(bf16_t)la5[1],(bf16_t)la5[2],(bf16_t)la5[3] };
    abf[3] = bf16x8{ (bf16_t)la6[0],(bf16_t)la6[1],(bf16_t)la6[2],(bf16_t)la6[3],
                     (bf16_t)la7[0],(bf16_t)la7[1],(bf16_t)la7[2],(bf16_t)la7[3] };
    __syncthreads();                 // Bs(k) visible
    if (k < 31) {                    // prefetch k+1; stays in flight across MFMA
      la0 = *(const f32x4*)(pr0); la1 = *(const f32x4*)(pr0+4); pr0 += 32;
      la2 = *(const f32x4*)(pr1); la3 = *(const f32x4*)(pr1+4); pr1 += 32;
      la4 = *(const f32x4*)(pr2); la5 = *(const f32x4*)(pr2+4); pr2 += 32;
      la6 = *(const f32x4*)(pr3); la7 = *(const f32x4*)(pr3+4); pr3 += 32;
      lb  = *(const bf16x8*)(gB); gB += 32;
    }
    bf16x8 bfv[4];
#pragma unroll
    for (int ni = 0; ni < 4; ni++) bfv[ni] = *(const bf16x8*)&Bs[bro[ni]];
#pragma unroll
    for (int m = 0; m < 4; m++)
#pragma unroll
      for (int ni = 0; ni < 4; ni++)
        acc[m][ni] = __builtin_amdgcn_mfma_f32_16x16x32_bf16(abf[m], bfv[ni], acc[m][ni], 0, 0, 0);
  }

  // ---- epilogue: C/D col = lane&15, row = l4*4 + jj ----
#pragma unroll
  for (int m = 0; m < 4; m++) {
#pragma unroll
    for (int jj = 0; jj < 4; jj++) {
      int rbw = wv*64 + m*16 + l4*4 + jj;
      if (rbw < nrows) {
        int r = rl[rbw];
        float s = tw[r];
        if (MODE == 1) {
          bf16_t* dst = scrb + (size_t)r*NDIM + n0 + lr;
#pragma unroll
          for (int ni = 0; ni < 4; ni++) dst[ni*16] = (bf16_t)(acc[m][ni][jj] * s);
        } else {
          float* dst = outp + (size_t)(r >> 1)*NDIM + n0 + lr;
#pragma unroll
          for (int ni = 0; ni < 4; ni++) atomicAdd(dst + ni*16, acc[m][ni][jj] * s);
        }
      }
    }
  }
}

// ---------------- 4. pair reduce (bf16 scratch -> fp32 out), 16B loads -------
__global__ void reduce_bf16_kernel(const bf16_t* __restrict__ scr, float* __restrict__ out) {
  int i = blockIdx.x * blockDim.x + threadIdx.x;   // one bf16x8 pair per thread
  int tk = i >> 8;                 // NDIM/8 = 256 chunks per row
  int h  = (i & 255) * 8;
  bf16x8 a = *(const bf16x8*)(scr + ((size_t)2*tk    )*NDIM + h);
  bf16x8 b = *(const bf16x8*)(scr + ((size_t)2*tk + 1)*NDIM + h);
  float4 o0 = { (float)a[0]+(float)b[0], (float)a[1]+(float)b[1],
                (float)a[2]+(float)b[2], (float)a[3]+(float)b[3] };
  float4 o1 = { (float)a[4]+(float)b[4], (float)a[5]+(float)b[5],
                (float)a[6]+(float)b[6], (float)a[7]+(float)b[7] };
  float* dst = out + (size_t)tk*NDIM + h;
  *(float4*)(dst)     = o0;
  *(float4*)(dst + 4) = o1;
}

// ---------------- launch ----------------
extern "C" void kernel_launch(void* const* d_in, const int* in_sizes, int n_in,
                              void* d_out, int out_size, void* d_ws, size_t ws_size,
                              hipStream_t stream) {
  const float* x      = (const float*)d_in[0];
  const float* w      = (const float*)d_in[1];
  const float* logits = (const float*)d_in[2];
  float* out = (float*)d_out;

  char* ws = (char*)d_ws;
  float*  tw      = (float*)(ws + OFF_TW);
  int*    cnt     = (int*)  (ws + OFF_CNT);
  int*    rowlist = (int*)  (ws + OFF_RL);
  bf16_t* wb      = (bf16_t*)(ws + OFF_WB);
  bf16_t* scrb    = (bf16_t*)(ws + OFF_SCR);

  hipMemsetAsync(cnt, 0, NEXP * sizeof(int), stream);
  routing_kernel<<<NTOK/256, 256, 0, stream>>>(logits, tw, cnt, rowlist);
  cvt_w_kernel<<<dim3(NDIM/64, KDIM/64, NEXP), 256, 0, stream>>>(w, wb);

  if (ws_size >= NEED_BF16) {
    gemm_kernel<1><<<GRID_G, 256, 0, stream>>>(x, wb, rowlist, cnt, tw, scrb, nullptr);
    reduce_bf16_kernel<<<NTOK*NDIM/8/256, 256, 0, stream>>>(scrb, out);
  } else {
    hipMemsetAsync(d_out, 0, (size_t)NTOK * NDIM * sizeof(float), stream);
    gemm_kernel<2><<<GRID_G, 256, 0, stream>>>(x, wb, rowlist, cnt, tw, nullptr, out);
  }
}

// Round 8
// 217.753 us; speedup vs baseline: 5.0645x; 5.0645x over previous
//
#include <hip/hip_runtime.h>
#include <hip/hip_bf16.h>

// ---------------- problem constants ----------------
#define NTOK   8192
#define TOPK   2
#define NROWS  (NTOK*TOPK)      // 16384
#define NEXP   8
#define KDIM   1024             // inner (INTER)
#define NDIM   2048             // output (HIDDEN)
#define TM     128              // tile rows
#define TN     256              // tile cols
#define BK     64
#define MAXYT  136              // sum ceil(cnt_e/128) <= 128+8
#define NXT    (NDIM/TN)        // 8
#define GRID_G (MAXYT*NXT)      // 1088 = 8*136

typedef __bf16 bf16_t;
typedef __bf16 bf16x8 __attribute__((ext_vector_type(8)));
typedef float  f32x4  __attribute__((ext_vector_type(4)));

static_assert(sizeof(bf16x8) == 16, "bf16x8 must be 16B");

// ---------------- ws layout (bytes); r1 proved ws_size >= 196MB ----------------
#define OFF_TW    ((size_t)0)                    // 16384 f32
#define OFF_INV   ((size_t)(1<<16))              // 16384 i32
#define OFF_CNT   ((size_t)(1<<17))              // 8 i32
#define OFF_RL    ((size_t)(1<<18))              // 8*16384 i32
#define OFF_XP    ((size_t)(1<<20))              // 16384*1024 bf16 = 32MB (permuted)
#define OFF_WB    ((size_t)(34u<<20))            // 8*2048*1024 bf16 = 32MB
#define OFF_SCR   ((size_t)(68u<<20))            // 16384*2048 bf16 = 64MB (permuted order)

__device__ __forceinline__ void gload_lds16(const bf16_t* g, const char* l) {
  __builtin_amdgcn_global_load_lds(
      (const __attribute__((address_space(1))) void*)g,
      (__attribute__((address_space(3))) void*)(void*)l, 16, 0, 0);
}

// ---------------- 1. routing: softmax + top2 + bucket ----------------
__global__ void routing_kernel(const float* __restrict__ logits,
                               float* __restrict__ tw,
                               int* __restrict__ cnt, int* __restrict__ rowlist) {
  int t = blockIdx.x * blockDim.x + threadIdx.x;
  if (t >= NTOK) return;
  float4 a = *(const float4*)(logits + (size_t)t*NEXP);
  float4 b = *(const float4*)(logits + (size_t)t*NEXP + 4);
  float l[8] = {a.x, a.y, a.z, a.w, b.x, b.y, b.z, b.w};
  float m = l[0];
#pragma unroll
  for (int i = 1; i < 8; i++) m = fmaxf(m, l[i]);
  float p[8], s = 0.f;
#pragma unroll
  for (int i = 0; i < 8; i++) { p[i] = __expf(l[i] - m); s += p[i]; }
  int e0 = 0; float b0 = p[0];
#pragma unroll
  for (int i = 1; i < 8; i++) if (p[i] > b0) { b0 = p[i]; e0 = i; }
  int e1 = (e0 == 0) ? 1 : 0; float b1 = p[e1];
#pragma unroll
  for (int i = 0; i < 8; i++) if (i != e0 && p[i] > b1) { b1 = p[i]; e1 = i; }
  float inv = 1.f / s;
  tw[2*t]   = b0 * inv;
  tw[2*t+1] = b1 * inv;
  int pos0 = atomicAdd(&cnt[e0], 1);
  rowlist[(size_t)e0*NROWS + pos0] = 2*t;
  int pos1 = atomicAdd(&cnt[e1], 1);
  rowlist[(size_t)e1*NROWS + pos1] = 2*t + 1;
}

// ---------------- 2. cvt_x_perm: x -> bf16, expert-sorted order; emit inv ----
// slot s in [0,NROWS): find expert e with s in [acc_e, acc_e+cnt_e); src row =
// rowlist[e*NROWS + s - acc_e]. Gather-read fp32 (coalesced in-row), write
// xp[s] sequential. inv[src] = s for the reduce.
__global__ void cvt_x_perm_kernel(const float* __restrict__ x,
                                  const int* __restrict__ cnt,
                                  const int* __restrict__ rowlist,
                                  bf16_t* __restrict__ xp,
                                  int* __restrict__ inv) {
  int s = blockIdx.x * 2 + (threadIdx.x >> 7);     // 2 rows per 256-thr block
  int c = threadIdx.x & 127;                       // col chunk (8 elems)
  int e = 0, base = 0, acc = 0;
#pragma unroll
  for (int ee = 0; ee < NEXP; ee++) {
    int ce = cnt[ee];
    if (s >= acc && s < acc + ce) { e = ee; base = acc; }
    acc += ce;
  }
  int src = rowlist[(size_t)e*NROWS + (s - base)];
  const float* sp = x + (size_t)src*KDIM + c*8;
  float4 v0 = *(const float4*)(sp);
  float4 v1 = *(const float4*)(sp + 4);
  bf16x8 o = { (bf16_t)v0.x, (bf16_t)v0.y, (bf16_t)v0.z, (bf16_t)v0.w,
               (bf16_t)v1.x, (bf16_t)v1.y, (bf16_t)v1.z, (bf16_t)v1.w };
  *(bf16x8*)(xp + (size_t)s*KDIM + c*8) = o;
  if (c == 0) inv[src] = s;
}

// ---------------- 3. convert+transpose w -> bf16 [E][N][K] ----------------
__global__ void cvt_w_kernel(const float* __restrict__ w, bf16_t* __restrict__ wb) {
  __shared__ float tf[64*65];
  int e  = blockIdx.z;
  int n0 = blockIdx.x * 64;
  int k0 = blockIdx.y * 64;
  int t  = threadIdx.x;
  const float* src = w + (size_t)e*KDIM*NDIM + (size_t)k0*NDIM + n0;
#pragma unroll
  for (int i = 0; i < 4; i++) {
    int idx = t + i*256;
    int kr  = idx >> 4;
    int nc4 = (idx & 15) * 4;
    float4 v = *(const float4*)(src + (size_t)kr*NDIM + nc4);
    tf[kr*65 + nc4+0] = v.x; tf[kr*65 + nc4+1] = v.y;
    tf[kr*65 + nc4+2] = v.z; tf[kr*65 + nc4+3] = v.w;
  }
  __syncthreads();
  bf16_t* dst = wb + (size_t)e*NDIM*KDIM + (size_t)n0*KDIM + k0;
#pragma unroll
  for (int i = 0; i < 2; i++) {
    int idx = t + i*256;
    int nr  = idx >> 3;
    int kc  = (idx & 7) * 8;
    bf16x8 o;
#pragma unroll
    for (int j = 0; j < 8; j++) o[j] = (bf16_t)tf[(kc+j)*65 + nr];
    *(bf16x8*)(dst + (size_t)nr*KDIM + kc) = o;
  }
}

// ---------------- 4. dense per-expert GEMM: 128x256, BK=64, single buffer ----
// 8 waves (2M x 4N), per-wave 64x64 out, 32 MFMA per barrier-pair (2x r2's
// amortization). A rows sequential from permuted xp; C rows sequential to scr.
// LDS 48KB: A[128][64] @0, B[256][64] @16384, row = 8 slots of 16B,
// phys slot = logical ^ (row&7). DMA dest linear in t (dest = base + t*16).
__global__ __launch_bounds__(512)
void gemm_kernel(const bf16_t* __restrict__ xp,     // [NROWS][KDIM] permuted
                 const bf16_t* __restrict__ wb,     // [NEXP][NDIM][KDIM]
                 const int*    __restrict__ cnt,
                 bf16_t*       __restrict__ scrb) { // [NROWS][NDIM] permuted
  __shared__ char smem[49152];

  // XCD-bijective swizzle: 1088 = 8*136, n-tile fastest
  int bid = blockIdx.x;
  int lin = (bid & 7) * (GRID_G/8) + (bid >> 3);
  int xt  = lin & (NXT-1);
  int yt  = lin >> 3;

  // inline worklist: expert + row range for this 128-row tile
  int e = -1, rowbase = 0, nrows = 0;
  {
    int a0 = 0, rb = 0;
#pragma unroll
    for (int ee = 0; ee < NEXP; ee++) {
      int c  = cnt[ee];
      int nt = (c + TM - 1) >> 7;
      if (yt >= a0 && yt < a0 + nt) {
        e = ee; rowbase = rb + (yt - a0)*TM;
        nrows = c - (yt - a0)*TM; if (nrows > TM) nrows = TM;
      }
      a0 += nt; rb += c;
    }
  }
  if (e < 0) return;
  const int n0 = xt * TN;

  const int t    = threadIdx.x;
  const int lane = t & 63;
  const int wv   = t >> 6;         // 0..7
  const int wm   = wv >> 2;        // 0..1
  const int wn   = wv & 3;         // 0..3
  const int lr   = lane & 15;
  const int l4   = lane >> 4;

  // ---- staging: thread t -> row t>>3 (+64i), phys slot t&7 ----
  // LDS offset = row*128 + phys*16 = t*16 + i*8192 (linear!). Source col =
  // (phys ^ (row&7))*8 with row&7 = (t>>3)&7.
  const int koff = ((t & 7) ^ ((t >> 3) & 7)) * 8;
  int ar0 = rowbase + (t >> 3);       if (ar0 > NROWS-1) ar0 = NROWS-1;
  int ar1 = rowbase + (t >> 3) + 64;  if (ar1 > NROWS-1) ar1 = NROWS-1;
  const bf16_t* gA0 = xp + (size_t)ar0*KDIM + koff;
  const bf16_t* gA1 = xp + (size_t)ar1*KDIM + koff;
  const bf16_t* gBb = wb + ((size_t)e*NDIM + n0 + (t >> 3))*KDIM + koff;
  const char* dA = &smem[t*16];
  const char* dB = &smem[16384 + t*16];

  // ---- fragment read offsets (byte, swizzled): addr = base + mi/ni*2048,
  // kk flips bit6 ----
  const int aoff0 = (wm*64 + lr)*128 + ((l4 ^ (lr & 7)) << 4);
  const int boff0 = 16384 + (wn*64 + lr)*128 + ((l4 ^ (lr & 7)) << 4);

  f32x4 acc[4][4] = {};

#pragma unroll 1
  for (int kt = 0; kt < KDIM/BK; ++kt) {
    __syncthreads();                 // previous reads done
    gload_lds16(gA0, dA);
    gload_lds16(gA1, dA + 8192);
    gload_lds16(gBb,            dB);
    gload_lds16(gBb + 64*KDIM,  dB + 8192);
    gload_lds16(gBb + 128*KDIM, dB + 16384);
    gload_lds16(gBb + 192*KDIM, dB + 24576);
    gA0 += BK; gA1 += BK; gBb += BK;
    __syncthreads();                 // staged data visible

    bf16x8 af[4][2], bf[4][2];
#pragma unroll
    for (int mi = 0; mi < 4; mi++) {
      af[mi][0] = *(const bf16x8*)&smem[aoff0 + mi*2048];
      af[mi][1] = *(const bf16x8*)&smem[(aoff0 + mi*2048) ^ 64];
    }
#pragma unroll
    for (int ni = 0; ni < 4; ni++) {
      bf[ni][0] = *(const bf16x8*)&smem[boff0 + ni*2048];
      bf[ni][1] = *(const bf16x8*)&smem[(boff0 + ni*2048) ^ 64];
    }
#pragma unroll
    for (int mi = 0; mi < 4; mi++)
#pragma unroll
      for (int ni = 0; ni < 4; ni++) {
        acc[mi][ni] = __builtin_amdgcn_mfma_f32_16x16x32_bf16(af[mi][0], bf[ni][0], acc[mi][ni], 0, 0, 0);
        acc[mi][ni] = __builtin_amdgcn_mfma_f32_16x16x32_bf16(af[mi][1], bf[ni][1], acc[mi][ni], 0, 0, 0);
      }
  }

  // ---- epilogue: sequential rows, no tw, no gather ----
#pragma unroll
  for (int mi = 0; mi < 4; mi++) {
#pragma unroll
    for (int jj = 0; jj < 4; jj++) {
      int rbw = wm*64 + mi*16 + l4*4 + jj;
      if (rbw < nrows) {
        bf16_t* dst = scrb + (size_t)(rowbase + rbw)*NDIM + n0 + wn*64 + lr;
#pragma unroll
        for (int ni = 0; ni < 4; ni++) dst[ni*16] = (bf16_t)acc[mi][ni][jj];
      }
    }
  }
}

// ---------------- 5. reduce: out[t] = tw0*scr[inv[2t]] + tw1*scr[inv[2t+1]] --
__global__ void reduce_kernel(const bf16_t* __restrict__ scr,
                              const int* __restrict__ inv,
                              const float* __restrict__ tw,
                              float* __restrict__ out) {
  int tk = blockIdx.x;                 // token
  int c  = threadIdx.x;                // 256 threads, 8 cols each
  int2  iv = *(const int2*)(inv + 2*tk);
  float w0 = tw[2*tk], w1 = tw[2*tk+1];
  bf16x8 a = *(const bf16x8*)(scr + (size_t)iv.x*NDIM + c*8);
  bf16x8 b = *(const bf16x8*)(scr + (size_t)iv.y*NDIM + c*8);
  float4 o0 = { w0*(float)a[0]+w1*(float)b[0], w0*(float)a[1]+w1*(float)b[1],
                w0*(float)a[2]+w1*(float)b[2], w0*(float)a[3]+w1*(float)b[3] };
  float4 o1 = { w0*(float)a[4]+w1*(float)b[4], w0*(float)a[5]+w1*(float)b[5],
                w0*(float)a[6]+w1*(float)b[6], w0*(float)a[7]+w1*(float)b[7] };
  float* dst = out + (size_t)tk*NDIM + c*8;
  *(float4*)(dst)     = o0;
  *(float4*)(dst + 4) = o1;
}

// ---------------- launch ----------------
extern "C" void kernel_launch(void* const* d_in, const int* in_sizes, int n_in,
                              void* d_out, int out_size, void* d_ws, size_t ws_size,
                              hipStream_t stream) {
  const float* x      = (const float*)d_in[0];
  const float* w      = (const float*)d_in[1];
  const float* logits = (const float*)d_in[2];
  float* out = (float*)d_out;

  char* ws = (char*)d_ws;
  float*  tw      = (float*)(ws + OFF_TW);
  int*    inv     = (int*)  (ws + OFF_INV);
  int*    cnt     = (int*)  (ws + OFF_CNT);
  int*    rowlist = (int*)  (ws + OFF_RL);
  bf16_t* xp      = (bf16_t*)(ws + OFF_XP);
  bf16_t* wb      = (bf16_t*)(ws + OFF_WB);
  bf16_t* scrb    = (bf16_t*)(ws + OFF_SCR);

  hipMemsetAsync(cnt, 0, NEXP * sizeof(int), stream);
  routing_kernel<<<NTOK/256, 256, 0, stream>>>(logits, tw, cnt, rowlist);
  cvt_x_perm_kernel<<<NROWS/2, 256, 0, stream>>>(x, cnt, rowlist, xp, inv);
  cvt_w_kernel<<<dim3(NDIM/64, KDIM/64, NEXP), 256, 0, stream>>>(w, wb);
  gemm_kernel<<<GRID_G, 512, 0, stream>>>(xp, wb, cnt, scrb);
  reduce_kernel<<<NTOK, 256, 0, stream>>>(scrb, inv, tw, out);
}